// Round 2
// baseline (86811.224 us; speedup 1.0000x reference)
//
#include <hip/hip_runtime.h>
#include <cmath>

// Problem constants
#define Tc   2048
#define OUTc 10

// Geometry: 4 groups x 16 batches; 64 blocks/group; block owns 8 h-dims x 4 gates (both layers)
#define NGRP 4
#define BPG  64
#define NTHR 256
#define KS   1280   // inAll row stride (floats): [x 64 | hA 512 | zeros 192 | hB 512]

// Workspace layout (float offsets)
#define WREG_FLOATS (64*4*7*8*64*4)            // [r][wave][q7][j8][lane64][4] = 3,670,016
#define OFF_BS0 WREG_FLOATS
#define OFF_BS1 (OFF_BS0 + 2048)
#define OFF_HA  (OFF_BS1 + 2048)               // [2 parity][4 g][16 b][512]
#define OFF_HB  (OFF_HA + 2*4*16*512)
#define OFF_BAR (OFF_HB + 2*4*16*512)
#define WS_FLOATS (OFF_BAR + 1024)

typedef __attribute__((ext_vector_type(2))) float f32x2;
typedef __attribute__((ext_vector_type(4))) float f32x4v;

#define ALOAD(p)    __hip_atomic_load((p), __ATOMIC_RELAXED, __HIP_MEMORY_SCOPE_AGENT)
#define ASTORE(p,v) __hip_atomic_store((p), (v), __ATOMIC_RELAXED, __HIP_MEMORY_SCOPE_AGENT)

// ---------------- prep: gather per-lane register-weight layout + bias sums ----------------
__global__ void prep_kernel(const float* __restrict__ Wih0, const float* __restrict__ Whh0,
                            const float* __restrict__ bih0, const float* __restrict__ bhh0,
                            const float* __restrict__ Wih1, const float* __restrict__ Whh1,
                            const float* __restrict__ bih1, const float* __restrict__ bhh1,
                            float* __restrict__ ws) {
    const int blk = blockIdx.x;
    const int t = threadIdx.x;
    if (blk < 1792) {
        // blk = (r*4 + w)*7 + q
        const int q = blk % 7;
        const int rw = blk / 7;
        const int w = rw & 3;
        const int rr = rw >> 2;
        for (int e = t * 8; e < t * 8 + 8; ++e) {
            const int j = e >> 8, l = (e >> 2) & 63, m = e & 3;
            const int col = w * 512 + rr * 8 + j;   // global gate-row
            float val;
            if (q < 3) {                             // layer0, inAll-space k in [0,768)
                const int kk = 256 * q + 4 * l + m;
                val = (kk < 64) ? Wih0[col * 64 + kk]
                    : (kk < 576) ? Whh0[col * 512 + (kk - 64)] : 0.f;
            } else {                                 // layer1, k1 in [0,1024)
                const int k1 = 256 * (q - 3) + 4 * l + m;
                val = (k1 < 512) ? Wih1[col * 512 + k1] : Whh1[col * 512 + (k1 - 512)];
            }
            ws[(size_t)blk * 2048 + e] = val;
        }
    } else {
        const int i = (blk - 1792) * 256 + t;        // 0..4095
        if (i < 2048) ws[OFF_BS0 + i] = bih0[i] + bhh0[i];
        else          ws[OFF_BS1 + (i - 2048)] = bih1[i - 2048] + bhh1[i - 2048];
    }
}

// ---------------- device helpers ----------------
__device__ __forceinline__ void pkfma(f32x2& a, f32x2 b, f32x2 c) {
    asm("v_pk_fma_f32 %0, %1, %2, %0" : "+v"(a) : "v"(b), "v"(c));
}

template<int CTRL>
__device__ __forceinline__ float dppadd(float x) {
    int m = __builtin_amdgcn_update_dpp(0, __float_as_int(x), CTRL, 0xf, 0xf, true);
    return x + __int_as_float(m);
}
__device__ __forceinline__ float rowred4(float x) {   // 16-lane row prefix-sum; lane 15 of each row = row total
    x = dppadd<0x111>(x);  // row_shr:1
    x = dppadd<0x112>(x);  // row_shr:2
    x = dppadd<0x114>(x);  // row_shr:4
    x = dppadd<0x118>(x);  // row_shr:8
    return x;
}
__device__ __forceinline__ float sigmf(float v) { return 1.f / (1.f + expf(-v)); }

#define ZACC \
  { _Pragma("unroll") for (int j = 0; j < 8; ++j) \
    _Pragma("unroll") for (int bb = 0; bb < 8; ++bb) { acc2[j][bb].x = 0.f; acc2[j][bb].y = 0.f; } }

#define MV_QUAD(Q, KOFF) \
  { _Pragma("unroll") for (int bb = 0; bb < 8; ++bb) { \
      const f32x4v vv = *(const f32x4v*)&inAll[(bh*8 + bb)*KS + (KOFF) + 4*lane]; \
      _Pragma("unroll") for (int j = 0; j < 8; ++j) { \
        pkfma(acc2[j][bb], w2[Q][j][0], vv.lo); \
        pkfma(acc2[j][bb], w2[Q][j][1], vv.hi); } } }

#define REDW(LAY) \
  { float red[8][8]; \
    _Pragma("unroll") for (int j = 0; j < 8; ++j) \
    _Pragma("unroll") for (int bb = 0; bb < 8; ++bb) \
      red[j][bb] = rowred4(acc2[j][bb].x + acc2[j][bb].y); \
    if ((lane & 15) == 15) { \
      const int row = lane >> 4; \
      _Pragma("unroll") for (int j = 0; j < 8; ++j) \
      _Pragma("unroll") for (int bq = 0; bq < 2; ++bq) { \
        f32x4v pk; \
        pk.x = red[j][bq*4+0]; pk.y = red[j][bq*4+1]; \
        pk.z = red[j][bq*4+2]; pk.w = red[j][bq*4+3]; \
        *(f32x4v*)&part[(((LAY)*4 + wv)*4 + row)*128 + j*16 + bh*8 + bq*4] = pk; } } }

// ---------------- persistent LSTM ----------------
__launch_bounds__(NTHR, 1)
__global__ void lstm_persistent(const float* __restrict__ x,
                                const float* __restrict__ Wlin,
                                const float* __restrict__ blin,
                                float* __restrict__ ws,
                                float* __restrict__ out) {
    const int g = blockIdx.x & 3;          // group -> XCD pair {g, g+4}
    const int r = blockIdx.x >> 2;         // rank in group: owns dims r*8..r*8+7
    const int tid = threadIdx.x;
    const int wv = tid >> 6;               // wave = gate index q
    const int lane = tid & 63;             // k-chunk within wave

    float* __restrict__ ghA = ws + OFF_HA;
    float* __restrict__ ghB = ws + OFF_HB;
    unsigned* bar = (unsigned*)(ws + OFF_BAR);
    unsigned* cnt = bar + g * 32;
    unsigned* gen = bar + 512 + g * 32;

    __shared__ __align__(16) float inAll[16 * KS];        // 80 KB: [b16][k 1280]
    __shared__ __align__(16) float part[2 * 4 * 4 * 8 * 16]; // 16 KB: [lay][q][row4][j8][b16]
    __shared__ float logit_s[160];

    // ---- load this lane's weights into registers (stationary for whole sequence) ----
    f32x2 w2[7][8][2];
    {
        const f32x4v* wr4 = (const f32x4v*)ws;
        const int base = (r * 4 + wv) * 7 * 8 * 64;
#pragma unroll
        for (int q = 0; q < 7; ++q)
#pragma unroll
            for (int j = 0; j < 8; ++j) {
                f32x4v t4 = wr4[base + (q * 8 + j) * 64 + lane];
                w2[q][j][0] = t4.lo;
                w2[q][j][1] = t4.hi;
            }
    }

    // ---- update-role constants (thread = (layer, batch, dim)) ----
    const int ul = tid >> 7, urem = tid & 127, ub = urem >> 3, uj = urem & 7;
    const float* bsl = ws + (ul ? OFF_BS1 : OFF_BS0);
    float biasv[4];
#pragma unroll
    for (int q = 0; q < 4; ++q) biasv[q] = bsl[q * 512 + r * 8 + uj];
    float* __restrict__ ghW = ul ? ghB : ghA;
    float creg = 0.f;

    // zero the layer0 K-pad region [576,768) once (weights there are 0, but LDS must not be NaN)
    for (int i = tid; i < 16 * 192; i += NTHR)
        inAll[(i / 192) * KS + 576 + (i % 192)] = 0.f;

    const int sb = tid >> 4, ck = tid & 15;   // staging roles: batch, 32-float chunk

    for (int s = 0; s <= Tc; ++s) {
        const int pin = (s + 1) & 1, pout = s & 1;

        // ---------- stage x(s), hA(s-1), hB(s-2) into LDS ----------
        if (s < Tc) {
            f32x4v xv = *(const f32x4v*)&x[(((size_t)(g * 16 + sb)) * Tc + s) * 64 + ck * 4];
            *(f32x4v*)&inAll[sb * KS + ck * 4] = xv;
        }
        {
            const float* hap = ghA + (((size_t)pin * 4 + g) * 16 + sb) * 512 + ck * 32;
            float* d = &inAll[sb * KS + 64 + ck * 32];
#pragma unroll
            for (int u = 0; u < 8; ++u) {
                f32x4v pk;
                pk.x = ALOAD(hap + u * 4 + 0); pk.y = ALOAD(hap + u * 4 + 1);
                pk.z = ALOAD(hap + u * 4 + 2); pk.w = ALOAD(hap + u * 4 + 3);
                *(f32x4v*)&d[u * 4] = pk;
            }
            const float* hbp = ghB + (((size_t)pin * 4 + g) * 16 + sb) * 512 + ck * 32;
            float* d2 = &inAll[sb * KS + 768 + ck * 32];
#pragma unroll
            for (int u = 0; u < 8; ++u) {
                f32x4v pk;
                pk.x = ALOAD(hbp + u * 4 + 0); pk.y = ALOAD(hbp + u * 4 + 1);
                pk.z = ALOAD(hbp + u * 4 + 2); pk.w = ALOAD(hbp + u * 4 + 3);
                *(f32x4v*)&d2[u * 4] = pk;
            }
        }
        __syncthreads();

        // ---------- matvec: wave wv = gate, lane = k-chunk, tile 8 cols x 8 batches x 2 halves ----------
        {
            f32x2 acc2[8][8];
            for (int bh = 0; bh < 2; ++bh) {
                if (s < Tc) {                     // layer 0: K = [x ; hA] (768 padded)
                    ZACC
                    MV_QUAD(0, 0) MV_QUAD(1, 256) MV_QUAD(2, 512)
                    REDW(0)
                }
                if (s >= 1) {                     // layer 1: K = [hA ; hB] (1024)
                    ZACC
                    MV_QUAD(3, 64) MV_QUAD(4, 320) MV_QUAD(5, 768) MV_QUAD(6, 1024)
                    REDW(1)
                }
            }
        }
        __syncthreads();

        // ---------- gate sums + cell update + h publish ----------
        {
            const bool act = (ul == 0) ? (s < Tc) : (s >= 1);
            if (act) {
                float gg[4];
#pragma unroll
                for (int q = 0; q < 4; ++q) {
                    const float* pp = &part[((ul * 4 + q) * 4) * 128 + uj * 16 + ub];
                    gg[q] = biasv[q] + pp[0] + pp[128] + pp[256] + pp[384];
                }
                const float iv = sigmf(gg[0]);
                const float fv = sigmf(gg[1]);
                const float gv_ = tanhf(gg[2]);
                const float ov = sigmf(gg[3]);
                creg = fv * creg + iv * gv_;
                const float hv = ov * tanhf(creg);
                ASTORE(&ghW[(((size_t)pout * 4 + g) * 16 + ub) * 512 + r * 8 + uj], hv);
            }
        }
        __syncthreads();   // drains vmcnt: all h atomic-stores completed (write-through) before signal

        // ---------- group barrier (flat, monotonic generation) ----------
        if (tid == 0) {
            unsigned gv = __hip_atomic_load(gen, __ATOMIC_RELAXED, __HIP_MEMORY_SCOPE_AGENT);
            unsigned old = __hip_atomic_fetch_add(cnt, 1u, __ATOMIC_ACQ_REL, __HIP_MEMORY_SCOPE_AGENT);
            if (old == BPG - 1) {
                __hip_atomic_store(cnt, 0u, __ATOMIC_RELAXED, __HIP_MEMORY_SCOPE_AGENT);
                __hip_atomic_store(gen, gv + 1u, __ATOMIC_RELEASE, __HIP_MEMORY_SCOPE_AGENT);
            } else {
                while (__hip_atomic_load(gen, __ATOMIC_ACQUIRE, __HIP_MEMORY_SCOPE_AGENT) == gv) {
                    __builtin_amdgcn_s_sleep(2);
                }
            }
        }
        __syncthreads();
    }

    // ---------- final projection + log_softmax (one block per group) ----------
    if (r == 0) {
        const float* hf = ghB + (((size_t)(Tc & 1) * 4 + g) * 16 + sb) * 512 + ck * 32;
        float* d = &inAll[sb * 512 + ck * 32];
#pragma unroll
        for (int u = 0; u < 8; ++u) {
            f32x4v pk;
            pk.x = ALOAD(hf + u * 4 + 0); pk.y = ALOAD(hf + u * 4 + 1);
            pk.z = ALOAD(hf + u * 4 + 2); pk.w = ALOAD(hf + u * 4 + 3);
            *(f32x4v*)&d[u * 4] = pk;
        }
        __syncthreads();
        if (tid < 16 * OUTc) {
            const int o = tid % OUTc, b = tid / OUTc;
            float sum = blin[o];
            for (int k = 0; k < 512; ++k) sum = fmaf(Wlin[o * 512 + k], inAll[b * 512 + k], sum);
            logit_s[b * OUTc + o] = sum;
        }
        __syncthreads();
        if (tid < 16) {
            float m = -1e30f;
#pragma unroll
            for (int o = 0; o < OUTc; ++o) m = fmaxf(m, logit_s[tid * OUTc + o]);
            float se = 0.f;
#pragma unroll
            for (int o = 0; o < OUTc; ++o) se += expf(logit_s[tid * OUTc + o] - m);
            const float lse = m + logf(se);
#pragma unroll
            for (int o = 0; o < OUTc; ++o)
                out[((size_t)(g * 16 + tid)) * OUTc + o] = logit_s[tid * OUTc + o] - lse;
        }
    }
}

extern "C" void kernel_launch(void* const* d_in, const int* in_sizes, int n_in,
                              void* d_out, int out_size, void* d_ws, size_t ws_size,
                              hipStream_t stream) {
    (void)in_sizes; (void)n_in; (void)out_size; (void)ws_size;
    const float* x    = (const float*)d_in[0];
    const float* Wih0 = (const float*)d_in[1];
    const float* Whh0 = (const float*)d_in[2];
    const float* bih0 = (const float*)d_in[3];
    const float* bhh0 = (const float*)d_in[4];
    const float* Wih1 = (const float*)d_in[5];
    const float* Whh1 = (const float*)d_in[6];
    const float* bih1 = (const float*)d_in[7];
    const float* bhh1 = (const float*)d_in[8];
    const float* Wlin = (const float*)d_in[9];
    const float* blin = (const float*)d_in[10];
    float* ws  = (float*)d_ws;
    float* out = (float*)d_out;

    // zero h double-buffers + barrier counters (ws is re-poisoned 0xAA before every timed launch)
    hipMemsetAsync((char*)d_ws + (size_t)OFF_HA * 4, 0,
                   (size_t)(WS_FLOATS - OFF_HA) * 4, stream);

    // gather weights into the per-lane register layout + bias sums
    prep_kernel<<<1792 + 16, 256, 0, stream>>>(Wih0, Whh0, bih0, bhh0,
                                               Wih1, Whh1, bih1, bhh1, ws);

    // persistent weight-stationary LSTM: 256 blocks (1/CU), 4 XCD-pair groups
    lstm_persistent<<<NGRP * BPG, NTHR, 0, stream>>>(x, Wlin, blin, ws, out);
}

// Round 3
// 33748.834 us; speedup vs baseline: 2.5723x; 2.5723x over previous
//
#include <hip/hip_runtime.h>
#include <cmath>

// Problem constants
#define Tc   2048
#define OUTc 10

// Geometry: 4 groups x 16 batches; 64 blocks/group; block owns 8 h-dims x 4 gates (both layers)
#define NGRP 4
#define BPG  64
#define NTHR 256
#define KS   1280   // inAll row stride (floats): [x 64 | hA 512 | zeros 192 | hB 512]

// Workspace layout (float offsets)
#define WREG_FLOATS (64*4*7*8*64*4)            // [r][wave][q7][j8][lane64][4] = 3,670,016
#define OFF_BS0 WREG_FLOATS
#define OFF_BS1 (OFF_BS0 + 2048)
#define OFF_HA  (OFF_BS1 + 2048)               // [2 parity][4 g][16 b][512]
#define OFF_HB  (OFF_HA + 2*4*16*512)
#define OFF_BAR (OFF_HB + 2*4*16*512)
#define WS_FLOATS (OFF_BAR + 1024)

typedef __attribute__((ext_vector_type(2))) float f32x2;
typedef __attribute__((ext_vector_type(4))) float f32x4v;

#define ALOAD(p)    __hip_atomic_load((p), __ATOMIC_RELAXED, __HIP_MEMORY_SCOPE_AGENT)
#define ASTORE(p,v) __hip_atomic_store((p), (v), __ATOMIC_RELAXED, __HIP_MEMORY_SCOPE_AGENT)

// ---------------- prep: gather per-lane register-weight layout + bias sums ----------------
__global__ void prep_kernel(const float* __restrict__ Wih0, const float* __restrict__ Whh0,
                            const float* __restrict__ bih0, const float* __restrict__ bhh0,
                            const float* __restrict__ Wih1, const float* __restrict__ Whh1,
                            const float* __restrict__ bih1, const float* __restrict__ bhh1,
                            float* __restrict__ ws) {
    const int blk = blockIdx.x;
    const int t = threadIdx.x;
    if (blk < 1792) {
        // blk = (r*4 + w)*7 + q
        const int q = blk % 7;
        const int rw = blk / 7;
        const int w = rw & 3;
        const int rr = rw >> 2;
        for (int e = t * 8; e < t * 8 + 8; ++e) {
            const int j = e >> 8, l = (e >> 2) & 63, m = e & 3;
            const int col = w * 512 + rr * 8 + j;   // global gate-row
            float val;
            if (q < 3) {                             // layer0, inAll-space k in [0,768)
                const int kk = 256 * q + 4 * l + m;
                val = (kk < 64) ? Wih0[col * 64 + kk]
                    : (kk < 576) ? Whh0[col * 512 + (kk - 64)] : 0.f;
            } else {                                 // layer1, k1 in [0,1024)
                const int k1 = 256 * (q - 3) + 4 * l + m;
                val = (k1 < 512) ? Wih1[col * 512 + k1] : Whh1[col * 512 + (k1 - 512)];
            }
            ws[(size_t)blk * 2048 + e] = val;
        }
    } else {
        const int i = (blk - 1792) * 256 + t;        // 0..4095
        if (i < 2048) ws[OFF_BS0 + i] = bih0[i] + bhh0[i];
        else          ws[OFF_BS1 + (i - 2048)] = bih1[i - 2048] + bhh1[i - 2048];
    }
}

// ---------------- device helpers ----------------
__device__ __forceinline__ void pkfma(f32x2& a, f32x2 b, f32x2 c) {
    asm("v_pk_fma_f32 %0, %1, %2, %0" : "+v"(a) : "v"(b), "v"(c));
}

template<int CTRL>
__device__ __forceinline__ float dppadd(float x) {
    int m = __builtin_amdgcn_update_dpp(0, __float_as_int(x), CTRL, 0xf, 0xf, true);
    return x + __int_as_float(m);
}
__device__ __forceinline__ float rowred4(float x) {   // 16-lane row prefix-sum; lane 15 of each row = row total
    x = dppadd<0x111>(x);  // row_shr:1
    x = dppadd<0x112>(x);  // row_shr:2
    x = dppadd<0x114>(x);  // row_shr:4
    x = dppadd<0x118>(x);  // row_shr:8
    return x;
}
__device__ __forceinline__ float sigmf(float v) { return 1.f / (1.f + expf(-v)); }

#define ZACC \
  { _Pragma("unroll") for (int j = 0; j < 8; ++j) \
    _Pragma("unroll") for (int bb = 0; bb < 8; ++bb) { acc2[j][bb].x = 0.f; acc2[j][bb].y = 0.f; } }

#define MV_QUAD(Q, KOFF) \
  { _Pragma("unroll") for (int bb = 0; bb < 8; ++bb) { \
      const f32x4v vv = *(const f32x4v*)&inAll[(bh*8 + bb)*KS + (KOFF) + 4*lane]; \
      _Pragma("unroll") for (int j = 0; j < 8; ++j) { \
        pkfma(acc2[j][bb], w2[Q][j][0], vv.lo); \
        pkfma(acc2[j][bb], w2[Q][j][1], vv.hi); } } }

#define REDW(LAY) \
  { float red[8][8]; \
    _Pragma("unroll") for (int j = 0; j < 8; ++j) \
    _Pragma("unroll") for (int bb = 0; bb < 8; ++bb) \
      red[j][bb] = rowred4(acc2[j][bb].x + acc2[j][bb].y); \
    if ((lane & 15) == 15) { \
      const int row = lane >> 4; \
      _Pragma("unroll") for (int j = 0; j < 8; ++j) \
      _Pragma("unroll") for (int bq = 0; bq < 2; ++bq) { \
        f32x4v pk; \
        pk.x = red[j][bq*4+0]; pk.y = red[j][bq*4+1]; \
        pk.z = red[j][bq*4+2]; pk.w = red[j][bq*4+3]; \
        *(f32x4v*)&part[(((LAY)*4 + wv)*4 + row)*128 + j*16 + bh*8 + bq*4] = pk; } } }

// ---------------- persistent LSTM ----------------
__launch_bounds__(NTHR, 1)
__global__ void lstm_persistent(const float* __restrict__ x,
                                const float* __restrict__ Wlin,
                                const float* __restrict__ blin,
                                float* __restrict__ ws,
                                float* __restrict__ out) {
    const int g = blockIdx.x & 3;          // group
    const int r = blockIdx.x >> 2;         // rank in group: owns dims r*8..r*8+7
    const int tid = threadIdx.x;
    const int wv = tid >> 6;               // wave = gate index q
    const int lane = tid & 63;             // k-chunk within wave

    float* __restrict__ ghA = ws + OFF_HA;
    float* __restrict__ ghB = ws + OFF_HB;
    unsigned* bar = (unsigned*)(ws + OFF_BAR);
    unsigned* cnt = bar + g * 32;
    unsigned* gen = bar + 512 + g * 32;

    __shared__ __align__(16) float inAll[16 * KS];        // 80 KB: [b16][k 1280]
    __shared__ __align__(16) float part[2 * 4 * 4 * 8 * 16]; // 16 KB: [lay][q][row4][j8][b16]
    __shared__ float logit_s[160];

    // ---- load this lane's weights into registers (stationary for whole sequence) ----
    f32x2 w2[7][8][2];
    {
        const f32x4v* wr4 = (const f32x4v*)ws;
        const int base = (r * 4 + wv) * 7 * 8 * 64;
#pragma unroll
        for (int q = 0; q < 7; ++q)
#pragma unroll
            for (int j = 0; j < 8; ++j) {
                f32x4v t4 = wr4[base + (q * 8 + j) * 64 + lane];
                w2[q][j][0] = t4.lo;
                w2[q][j][1] = t4.hi;
            }
    }

    // ---- update-role constants (thread = (layer, batch, dim)) ----
    const int ul = tid >> 7, urem = tid & 127, ub = urem >> 3, uj = urem & 7;
    const float* bsl = ws + (ul ? OFF_BS1 : OFF_BS0);
    float biasv[4];
#pragma unroll
    for (int q = 0; q < 4; ++q) biasv[q] = bsl[q * 512 + r * 8 + uj];
    float* __restrict__ ghW = ul ? ghB : ghA;
    float creg = 0.f;

    // zero the layer0 K-pad region [576,768) once (weights there are 0, but LDS must not be NaN)
    for (int i = tid; i < 16 * 192; i += NTHR)
        inAll[(i / 192) * KS + 576 + (i % 192)] = 0.f;

    const int xb = tid >> 4, xc = tid & 15;   // x-staging roles

    for (int s = 0; s <= Tc; ++s) {
        const int pin = (s + 1) & 1, pout = s & 1;

        // ---------- stage x(s), hA(s-1), hB(s-2) into LDS ----------
        {
            // 16 bypassing 16B loads (sc0 sc1: LLC-fresh, cross-XCD coherent), batched issue
            f32x4v stA[8], stB[8];
            const size_t hbase = ((size_t)pin * 4 + g) * (16 * 512);
            const float* pA = ghA + hbase + 4 * tid;
            const float* pB = ghB + hbase + 4 * tid;
#pragma unroll
            for (int u = 0; u < 8; ++u)
                asm volatile("global_load_dwordx4 %0, %1, off sc0 sc1"
                             : "=v"(stA[u]) : "v"(pA + 1024 * u));
#pragma unroll
            for (int u = 0; u < 8; ++u)
                asm volatile("global_load_dwordx4 %0, %1, off sc0 sc1"
                             : "=v"(stB[u]) : "v"(pB + 1024 * u));
            f32x4v xv;
            if (s < Tc)
                xv = *(const f32x4v*)&x[(((size_t)(g * 16 + xb)) * Tc + s) * 64 + xc * 4];
            asm volatile("s_waitcnt vmcnt(0)" ::: "memory");   // all 16 loads landed
#pragma unroll
            for (int u = 0; u < 8; ++u) {
                const int m = tid + 256 * u;                    // b128 chunk id, lane-consecutive
                *(f32x4v*)&inAll[(m >> 7) * KS + 64  + (m & 127) * 4] = stA[u];
                *(f32x4v*)&inAll[(m >> 7) * KS + 768 + (m & 127) * 4] = stB[u];
            }
            if (s < Tc) *(f32x4v*)&inAll[xb * KS + xc * 4] = xv;
        }
        __syncthreads();

        // ---------- matvec: wave wv = gate, lane = k-chunk, tile 8 cols x 8 batches x 2 halves ----------
        {
            f32x2 acc2[8][8];
            for (int bh = 0; bh < 2; ++bh) {
                if (s < Tc) {                     // layer 0: K = [x ; hA] (768 padded)
                    ZACC
                    MV_QUAD(0, 0) MV_QUAD(1, 256) MV_QUAD(2, 512)
                    REDW(0)
                }
                if (s >= 1) {                     // layer 1: K = [hA ; hB] (1024)
                    ZACC
                    MV_QUAD(3, 64) MV_QUAD(4, 320) MV_QUAD(5, 768) MV_QUAD(6, 1024)
                    REDW(1)
                }
            }
        }
        __syncthreads();

        // ---------- gate sums + cell update + h publish ----------
        {
            const bool act = (ul == 0) ? (s < Tc) : (s >= 1);
            if (act) {
                float gg[4];
#pragma unroll
                for (int q = 0; q < 4; ++q) {
                    const float* pp = &part[((ul * 4 + q) * 4) * 128 + uj * 16 + ub];
                    gg[q] = biasv[q] + pp[0] + pp[128] + pp[256] + pp[384];
                }
                const float iv = sigmf(gg[0]);
                const float fv = sigmf(gg[1]);
                const float gv_ = tanhf(gg[2]);
                const float ov = sigmf(gg[3]);
                creg = fv * creg + iv * gv_;
                const float hv = ov * tanhf(creg);
                ASTORE(&ghW[(((size_t)pout * 4 + g) * 16 + ub) * 512 + r * 8 + uj], hv);
            }
        }
        __syncthreads();   // implicit vmcnt(0): all h stores retired at LLC before arrival

        // ---------- group barrier: ALL-RELAXED (no L2 writeback/invalidate in loop) ----------
        if (tid == 0) {
            unsigned gv = ALOAD(gen);   // == G (can't advance without our arrival)
            unsigned old = __hip_atomic_fetch_add(cnt, 1u, __ATOMIC_RELAXED,
                                                  __HIP_MEMORY_SCOPE_AGENT);
            if (old == BPG - 1) {
                ASTORE(cnt, 0u);
                asm volatile("s_waitcnt vmcnt(0)" ::: "memory");  // cnt reset visible before gen bump
                ASTORE(gen, gv + 1u);
            } else {
                while (ALOAD(gen) == gv) {
                    __builtin_amdgcn_s_sleep(2);
                }
            }
        }
        __syncthreads();
    }

    // ---------- final projection + log_softmax (one block per group) ----------
    if (r == 0) {
        const float* hf = ghB + (((size_t)(Tc & 1) * 4 + g) * 16 + xb) * 512 + xc * 32;
        float* d = &inAll[xb * 512 + xc * 32];
#pragma unroll
        for (int u = 0; u < 8; ++u) {
            f32x4v pk;
            pk.x = ALOAD(hf + u * 4 + 0); pk.y = ALOAD(hf + u * 4 + 1);
            pk.z = ALOAD(hf + u * 4 + 2); pk.w = ALOAD(hf + u * 4 + 3);
            *(f32x4v*)&d[u * 4] = pk;
        }
        __syncthreads();
        if (tid < 16 * OUTc) {
            const int o = tid % OUTc, b = tid / OUTc;
            float sum = blin[o];
            for (int k = 0; k < 512; ++k) sum = fmaf(Wlin[o * 512 + k], inAll[b * 512 + k], sum);
            logit_s[b * OUTc + o] = sum;
        }
        __syncthreads();
        if (tid < 16) {
            float m = -1e30f;
#pragma unroll
            for (int o = 0; o < OUTc; ++o) m = fmaxf(m, logit_s[tid * OUTc + o]);
            float se = 0.f;
#pragma unroll
            for (int o = 0; o < OUTc; ++o) se += expf(logit_s[tid * OUTc + o] - m);
            const float lse = m + logf(se);
#pragma unroll
            for (int o = 0; o < OUTc; ++o)
                out[((size_t)(g * 16 + tid)) * OUTc + o] = logit_s[tid * OUTc + o] - lse;
        }
    }
}

extern "C" void kernel_launch(void* const* d_in, const int* in_sizes, int n_in,
                              void* d_out, int out_size, void* d_ws, size_t ws_size,
                              hipStream_t stream) {
    (void)in_sizes; (void)n_in; (void)out_size; (void)ws_size;
    const float* x    = (const float*)d_in[0];
    const float* Wih0 = (const float*)d_in[1];
    const float* Whh0 = (const float*)d_in[2];
    const float* bih0 = (const float*)d_in[3];
    const float* bhh0 = (const float*)d_in[4];
    const float* Wih1 = (const float*)d_in[5];
    const float* Whh1 = (const float*)d_in[6];
    const float* bih1 = (const float*)d_in[7];
    const float* bhh1 = (const float*)d_in[8];
    const float* Wlin = (const float*)d_in[9];
    const float* blin = (const float*)d_in[10];
    float* ws  = (float*)d_ws;
    float* out = (float*)d_out;

    // zero h double-buffers + barrier counters (ws is re-poisoned 0xAA before every timed launch)
    hipMemsetAsync((char*)d_ws + (size_t)OFF_HA * 4, 0,
                   (size_t)(WS_FLOATS - OFF_HA) * 4, stream);

    // gather weights into the per-lane register layout + bias sums
    prep_kernel<<<1792 + 16, 256, 0, stream>>>(Wih0, Whh0, bih0, bhh0,
                                               Wih1, Whh1, bih1, bhh1, ws);

    // persistent weight-stationary LSTM: 256 blocks (1/CU), 4 groups
    lstm_persistent<<<NGRP * BPG, NTHR, 0, stream>>>(x, Wlin, blin, ws, out);
}

// Round 4
// 33529.425 us; speedup vs baseline: 2.5891x; 1.0065x over previous
//
#include <hip/hip_runtime.h>
#include <cmath>

// Problem constants
#define Tc   2048
#define OUTc 10

// Geometry: 4 groups x 16 batches; 64 blocks/group; block owns 8 h-dims (all 4 gates, both layers)
// 512 threads = 8 waves = (gate q x k-half kh); 2 waves/SIMD, 1 block/CU.
#define NGRP 4
#define BPG  64
#define NTHR 512
#define KS   1280   // inAll row stride (floats): [x 64 | hA 512 | zeros 192 | hB 512]
#define PR   132    // part row stride (8 j * 16 b + 4 pad)

// Workspace layout (float offsets)
#define WREG_FLOATS (64*8*7*8*128)             // [r][wave8][oct7][j8][128] = 3,670,016
#define OFF_BS0 WREG_FLOATS
#define OFF_BS1 (OFF_BS0 + 2048)
#define OFF_HA  (OFF_BS1 + 2048)               // [2 parity][4 g][16 b][512]
#define OFF_HB  (OFF_HA + 2*4*16*512)
#define OFF_BAR (OFF_HB + 2*4*16*512)          // uint flags[4][64][16] (64B apart)
#define WS_FLOATS (OFF_BAR + 4096)

typedef __attribute__((ext_vector_type(2))) float f32x2;
typedef __attribute__((ext_vector_type(4))) float f32x4v;

#define ALOAD(p)    __hip_atomic_load((p), __ATOMIC_RELAXED, __HIP_MEMORY_SCOPE_AGENT)
#define ASTORE(p,v) __hip_atomic_store((p), (v), __ATOMIC_RELAXED, __HIP_MEMORY_SCOPE_AGENT)

// ---------------- prep: gather per-lane register-weight layout + bias sums ----------------
__global__ void prep_kernel(const float* __restrict__ Wih0, const float* __restrict__ Whh0,
                            const float* __restrict__ bih0, const float* __restrict__ bhh0,
                            const float* __restrict__ Wih1, const float* __restrict__ Whh1,
                            const float* __restrict__ bih1, const float* __restrict__ bhh1,
                            float* __restrict__ ws) {
    const int blk = blockIdx.x;
    const int t = threadIdx.x;
    if (blk < 1792) {
        for (int u = 0; u < 8; ++u) {
            const int flat = blk * 2048 + t * 8 + u;
            const int rw = flat / 7168;          // (r*8 + wv)
            const int rem = flat % 7168;
            const int o = rem >> 10;             // oct 0..6
            const int rem2 = rem & 1023;
            const int j = rem2 >> 7;
            const int e2 = rem2 & 127;           // 2*lane + m
            const int r = rw >> 3, wv = rw & 7;
            const int q = wv >> 1, kh = wv & 1;
            const int col = q * 512 + r * 8 + j;
            const int off = (o < 3) ? (kh * 384 + o * 128 + e2)
                                    : ((kh ? 768 : 64) + (o - 3) * 128 + e2);
            float val;
            if (o < 3) {   // layer 0: inAll-space [x64 | hA512 | zero192]
                val = (off < 64) ? Wih0[col * 64 + off]
                    : (off < 576) ? Whh0[col * 512 + (off - 64)] : 0.f;
            } else {       // layer 1: [64,576)=hA -> Wih1, [768,1280)=hB -> Whh1
                val = (off < 576) ? Wih1[col * 512 + (off - 64)]
                                  : Whh1[col * 512 + (off - 768)];
            }
            ws[flat] = val;
        }
    } else {
        for (int u = 0; u < 8; ++u) {
            const int i = (blk - 1792) * 2048 + t * 8 + u;   // 0..4095
            if (i < 2048) ws[OFF_BS0 + i] = bih0[i] + bhh0[i];
            else          ws[OFF_BS1 + (i - 2048)] = bih1[i - 2048] + bhh1[i - 2048];
        }
    }
}

// ---------------- device helpers ----------------
__device__ __forceinline__ void pkfma(f32x2& a, f32x2 b, f32x2 c) {
    asm("v_pk_fma_f32 %0, %1, %2, %0" : "+v"(a) : "v"(b), "v"(c));
}

template<int CTRL>
__device__ __forceinline__ float dppadd(float x) {
    int m = __builtin_amdgcn_update_dpp(0, __float_as_int(x), CTRL, 0xf, 0xf, true);
    return x + __int_as_float(m);
}
__device__ __forceinline__ float rowred16(float x) {  // 16-lane prefix sum; lane 15 of row = total
    x = dppadd<0x111>(x);
    x = dppadd<0x112>(x);
    x = dppadd<0x114>(x);
    x = dppadd<0x118>(x);
    return x;
}
__device__ __forceinline__ float sigmf(float v) { return 1.f / (1.f + expf(-v)); }

#define ZACC \
  { _Pragma("unroll") for (int j = 0; j < 8; ++j) \
    _Pragma("unroll") for (int bb = 0; bb < 4; ++bb) { acc2[j][bb].x = 0.f; acc2[j][bb].y = 0.f; } }

// one 128-float K "oct": lane reads f32x2 at koff + 2*lane, FMAs into 8 cols x 4 batches
#define MV_OCT(O, KOFF) \
  { _Pragma("unroll") for (int bb = 0; bb < 4; ++bb) { \
      const f32x2 vv = *(const f32x2*)&inAll[(bp * 4 + bb) * KS + (KOFF) + 2 * lane]; \
      _Pragma("unroll") for (int j = 0; j < 8; ++j) \
        pkfma(acc2[j][bb], w2[O][j], vv); } }

// reduce 16-lane rows; lane 15/31/47/63 writes one b128 (4 batches) per col j
#define REDW(LAY) \
  { const int pbase = (((LAY) * 4 + q) * 2 + kh) * 4 + (lane >> 4); \
    _Pragma("unroll") for (int j = 0; j < 8; ++j) { \
      float r0 = rowred16(acc2[j][0].x + acc2[j][0].y); \
      float r1 = rowred16(acc2[j][1].x + acc2[j][1].y); \
      float r2 = rowred16(acc2[j][2].x + acc2[j][2].y); \
      float r3 = rowred16(acc2[j][3].x + acc2[j][3].y); \
      if ((lane & 15) == 15) { \
        f32x4v pk; pk.x = r0; pk.y = r1; pk.z = r2; pk.w = r3; \
        *(f32x4v*)&part[pbase * PR + j * 16 + bp * 4] = pk; } } }

// ---------------- persistent LSTM ----------------
__launch_bounds__(NTHR, 2)
__global__ void lstm_persistent(const float* __restrict__ x,
                                const float* __restrict__ Wlin,
                                const float* __restrict__ blin,
                                float* __restrict__ ws,
                                float* __restrict__ out) {
    const int g = blockIdx.x & 3;          // group
    const int r = blockIdx.x >> 2;         // rank: owns dims r*8..r*8+7
    const int tid = threadIdx.x;
    const int wv = tid >> 6;               // wave 0..7
    const int lane = tid & 63;
    const int q = wv >> 1;                 // gate
    const int kh = wv & 1;                 // k-half

    float* __restrict__ ghA = ws + OFF_HA;
    float* __restrict__ ghB = ws + OFF_HB;
    unsigned* flags = (unsigned*)(ws + OFF_BAR);
    unsigned* myflag = flags + (size_t)(g * 64 + r) * 16;
    const unsigned* pollp = flags + (size_t)(g * 64 + lane) * 16;

    __shared__ __align__(16) float inAll[16 * KS];          // 80 KB [b16][k1280]
    __shared__ __align__(16) float part[2 * 4 * 2 * 4 * PR]; // 33 KB [lay][q][kh][row][j8 b16 +pad]
    __shared__ float logit_s[160];

    // ---- stationary weights: 56 f32x2 per lane ----
    f32x2 w2[7][8];
    {
        const f32x2* wp = (const f32x2*)ws + (size_t)(r * 8 + wv) * 3584 + lane;
#pragma unroll
        for (int o = 0; o < 7; ++o)
#pragma unroll
            for (int j = 0; j < 8; ++j)
                w2[o][j] = wp[(o * 8 + j) * 64];
    }
    const int l0base = kh * 384;           // L0 octs at l0base + {0,128,256}
    const int l1base = kh ? 768 : 64;      // L1 octs at l1base + {0,128,256,384}

    // ---- update-role constants (256 active threads: layer, batch, dim) ----
    const int ul = tid >> 7;               // valid for tid<256
    const int urem = tid & 127;
    const int uj = urem >> 4, ub = urem & 15;
    const float* bsl = ws + (ul ? OFF_BS1 : OFF_BS0);
    float biasv[4];
#pragma unroll
    for (int qq = 0; qq < 4; ++qq) biasv[qq] = bsl[qq * 512 + r * 8 + uj];
    float* __restrict__ ghW = ul ? ghB : ghA;
    float creg = 0.f;

    // zero the layer0 K-pad region [576,768) once
    for (int c = tid; c < 768; c += NTHR)
        *(f32x4v*)&inAll[(c / 48) * KS + 576 + (c % 48) * 4] = f32x4v{0.f, 0.f, 0.f, 0.f};

    const int xb = tid >> 5, xd = (tid & 31) * 2;   // x staging role

    for (int s = 0; s <= Tc; ++s) {
        const int pin = (s + 1) & 1, pout = s & 1;

        // ---------- stage x(s), hA, hB into LDS ----------
        {
            f32x4v stA[4], stB[4];
            const size_t hbase = ((size_t)pin * 4 + g) * (16 * 512);
            const float* pA = ghA + hbase + 4 * tid;
            const float* pB = ghB + hbase + 4 * tid;
#pragma unroll
            for (int u = 0; u < 4; ++u)
                asm volatile("global_load_dwordx4 %0, %1, off sc0 sc1"
                             : "=v"(stA[u]) : "v"(pA + 2048 * u));
#pragma unroll
            for (int u = 0; u < 4; ++u)
                asm volatile("global_load_dwordx4 %0, %1, off sc0 sc1"
                             : "=v"(stB[u]) : "v"(pB + 2048 * u));
            f32x2 xv;
            if (s < Tc)
                xv = *(const f32x2*)&x[(((size_t)(g * 16 + xb)) * Tc + s) * 64 + xd];
            asm volatile("s_waitcnt vmcnt(0)" ::: "memory");
#pragma unroll
            for (int u = 0; u < 4; ++u) {
                const int c = tid + 512 * u;     // 16B chunk id
                *(f32x4v*)&inAll[(c >> 7) * KS + 64  + (c & 127) * 4] = stA[u];
                *(f32x4v*)&inAll[(c >> 7) * KS + 768 + (c & 127) * 4] = stB[u];
            }
            if (s < Tc) *(f32x2*)&inAll[xb * KS + xd] = xv;
        }
        __syncthreads();   // #1

        // ---------- matvec: 4 batch-passes of 4 ----------
        {
            f32x2 acc2[8][4];
            for (int bp = 0; bp < 4; ++bp) {
                if (s < Tc) {                       // layer 0
                    ZACC
                    MV_OCT(0, l0base) MV_OCT(1, l0base + 128) MV_OCT(2, l0base + 256)
                    REDW(0)
                }
                if (s >= 1) {                       // layer 1
                    ZACC
                    MV_OCT(3, l1base) MV_OCT(4, l1base + 128)
                    MV_OCT(5, l1base + 256) MV_OCT(6, l1base + 384)
                    REDW(1)
                }
            }
        }
        __syncthreads();   // #2

        // ---------- gate sums + cell update + h publish (256 threads) ----------
        if (tid < 256) {
            const bool act = (ul == 0) ? (s < Tc) : (s >= 1);
            if (act) {
                float gg[4];
#pragma unroll
                for (int qq = 0; qq < 4; ++qq) {
                    float sum = biasv[qq];
#pragma unroll
                    for (int p8 = 0; p8 < 8; ++p8)   // kh2 x row4
                        sum += part[(((ul * 4 + qq) * 2) * 4 + p8) * PR + uj * 16 + ub];
                    gg[qq] = sum;
                }
                const float iv = sigmf(gg[0]);
                const float fv = sigmf(gg[1]);
                const float gv_ = tanhf(gg[2]);
                const float ov = sigmf(gg[3]);
                creg = fv * creg + iv * gv_;
                const float hv = ov * tanhf(creg);
                ASTORE(&ghW[(((size_t)pout * 4 + g) * 16 + ub) * 512 + r * 8 + uj], hv);
            }
        }
        __syncthreads();   // #3: drains vmcnt -> all h stores at LLC

        // ---------- flag publish + distributed poll (wave 0 only) ----------
        if (tid == 0) ASTORE(myflag, (unsigned)(s + 1));
        if (wv == 0) {
            const unsigned tgt = (unsigned)(s + 1);
            unsigned v;
            for (;;) {
                asm volatile("global_load_dword %0, %1, off sc0 sc1\n\ts_waitcnt vmcnt(0)"
                             : "=v"(v) : "v"(pollp) : "memory");
                if (__all((int)(v >= tgt))) break;
                __builtin_amdgcn_s_sleep(1);
            }
        }
        __syncthreads();   // #4
    }

    // ---------- final projection + log_softmax (one block per group) ----------
    if (r == 0) {
        const float* hf = ghB + (((size_t)(Tc & 1) * 4 + g) * 16) * 512;
        // reuse inAll[b][0..511] as the gather buffer (tid covers 16*512/16)
        {
            const int b = tid >> 5, c0 = (tid & 31) * 16;
            for (int u = 0; u < 16; ++u)
                inAll[b * 512 + c0 + u] = ALOAD(hf + b * 512 + c0 + u);
        }
        __syncthreads();
        if (tid < 16 * OUTc) {
            const int o = tid % OUTc, b = tid / OUTc;
            float sum = blin[o];
            for (int k = 0; k < 512; ++k) sum = fmaf(Wlin[o * 512 + k], inAll[b * 512 + k], sum);
            logit_s[b * OUTc + o] = sum;
        }
        __syncthreads();
        if (tid < 16) {
            float m = -1e30f;
#pragma unroll
            for (int o = 0; o < OUTc; ++o) m = fmaxf(m, logit_s[tid * OUTc + o]);
            float se = 0.f;
#pragma unroll
            for (int o = 0; o < OUTc; ++o) se += expf(logit_s[tid * OUTc + o] - m);
            const float lse = m + logf(se);
#pragma unroll
            for (int o = 0; o < OUTc; ++o)
                out[((size_t)(g * 16 + tid)) * OUTc + o] = logit_s[tid * OUTc + o] - lse;
        }
    }
}

extern "C" void kernel_launch(void* const* d_in, const int* in_sizes, int n_in,
                              void* d_out, int out_size, void* d_ws, size_t ws_size,
                              hipStream_t stream) {
    (void)in_sizes; (void)n_in; (void)out_size; (void)ws_size;
    const float* x    = (const float*)d_in[0];
    const float* Wih0 = (const float*)d_in[1];
    const float* Whh0 = (const float*)d_in[2];
    const float* bih0 = (const float*)d_in[3];
    const float* bhh0 = (const float*)d_in[4];
    const float* Wih1 = (const float*)d_in[5];
    const float* Whh1 = (const float*)d_in[6];
    const float* bih1 = (const float*)d_in[7];
    const float* bhh1 = (const float*)d_in[8];
    const float* Wlin = (const float*)d_in[9];
    const float* blin = (const float*)d_in[10];
    float* ws  = (float*)d_ws;
    float* out = (float*)d_out;

    // zero h double-buffers + flags (ws is re-poisoned 0xAA before every timed launch)
    hipMemsetAsync((char*)d_ws + (size_t)OFF_HA * 4, 0,
                   (size_t)(WS_FLOATS - OFF_HA) * 4, stream);

    // gather weights into the per-lane register layout + bias sums
    prep_kernel<<<1792 + 2, 256, 0, stream>>>(Wih0, Whh0, bih0, bhh0,
                                              Wih1, Whh1, bih1, bhh1, ws);

    // persistent weight-stationary LSTM: 256 blocks (1/CU, 8 waves), 4 groups
    lstm_persistent<<<NGRP * BPG, NTHR, 0, stream>>>(x, Wlin, blin, ws, out);
}

// Round 8
// 9311.710 us; speedup vs baseline: 9.3228x; 3.6008x over previous
//
#include <hip/hip_runtime.h>
#include <cmath>

// Problem constants
#define Tc   2048
#define OUTc 10

// Geometry: 4 groups x 16 batches; 64 blocks/group; block owns 8 h-dims (4 gates, 2 layers)
// 512 threads = 8 waves = (layer, Mtile, Khalf); MFMA 16x16x32 **fp16**, 2-term hi/lo split
// (lo plane pre-scaled by 2^12; 3 MFMAs/tile: hh->accH, h*lo+lo*h->accM; g = accH + accM/4096).
// h exchange: f32 planes (round-4/7 proven protocol); fp16 conversion is block-local at stage.
#define NGRP 4
#define BPG  64
#define NTHR 512
#define KP   1096            // V row stride in f16 elems: [x 64 | hA 512 | hB 512] + 8 pad
#define PST  20              // part m-stride in floats (bank-spread)

// Compact fragment packing: waves 0-3 (layer0) 18 slots (9 ktiles x hi/lo),
// waves 4-7 (layer1) 32 slots. 200 slots/rank, 64 ranks, 1 KB/slot = 12.5 MiB.
#define SLOT_BASE(r, w) ((r) * 200 + ((w) < 4 ? (w) * 18 : 72 + ((w) - 4) * 32))

// Workspace layout (float offsets) — 13.03 MiB total
#define WFRAG_FLOATS (64 * 200 * 64 * 4)   // 3,276,800
#define OFF_BS0 WFRAG_FLOATS
#define OFF_BS1 (OFF_BS0 + 2048)
#define OFF_HA  (OFF_BS1 + 2048)           // f32 [2 par][4 g][16 b][512] = 65536
#define OFF_HB  (OFF_HA + 65536)
#define OFF_BAR (OFF_HB + 65536)           // uint flags[4][64][16]
#define WS_FLOATS (OFF_BAR + 4096)

typedef __attribute__((ext_vector_type(2))) float f32x2;
typedef __attribute__((ext_vector_type(4))) float f32x4v;
typedef _Float16 f16t;
typedef __attribute__((ext_vector_type(8))) _Float16 half8;
typedef unsigned short u16t;
typedef unsigned int   u32t;

#define ALOAD(p)    __hip_atomic_load((p), __ATOMIC_RELAXED, __HIP_MEMORY_SCOPE_AGENT)
#define ASTORE(p,v) __hip_atomic_store((p), (v), __ATOMIC_RELAXED, __HIP_MEMORY_SCOPE_AGENT)

__device__ __forceinline__ void f16split(float v, u16t& hb, u16t& lb) {
    const f16t h = (f16t)v;                          // RNE, 11 mantissa bits
    const f16t l = (f16t)((v - (float)h) * 4096.f);  // residual, pre-scaled 2^12
    hb = __builtin_bit_cast(u16t, h);
    lb = __builtin_bit_cast(u16t, l);
}
__device__ __forceinline__ float sigmf(float v) { return 1.f / (1.f + expf(-v)); }

// convert 4 f32 -> 4 f16-hi + 4 f16-lo(scaled), write 8B to each plane
__device__ __forceinline__ void stash4(u16t* vh, u16t* vl, f32x4v v) {
    u16t h[4], l[4];
    f16split(v.x, h[0], l[0]); f16split(v.y, h[1], l[1]);
    f16split(v.z, h[2], l[2]); f16split(v.w, h[3], l[3]);
    uint2 hp; hp.x = (u32t)h[0] | ((u32t)h[1] << 16); hp.y = (u32t)h[2] | ((u32t)h[3] << 16);
    uint2 lp; lp.x = (u32t)l[0] | ((u32t)l[1] << 16); lp.y = (u32t)l[2] | ((u32t)l[3] << 16);
    *(uint2*)vh = hp;
    *(uint2*)vl = lp;
}

// ---------------- prep: per-lane MFMA A-fragments (fp16 hi/lo) + bias sums ----------------
// A frag (16x16x32): lane l holds row m=l&15, k = 8*(l>>4)+e (e=0..7).
// Waves: wv<4: layer0 (mt=wv&1, kh=(wv&3)>>1, K=2x288); wv>=4: layer1 (same roles, K=2x512).
// Mtile mt holds gates {2mt, 2mt+1}; row m = (gate&1)*8 + j.
__global__ void prep_kernel(const float* __restrict__ Wih0, const float* __restrict__ Whh0,
                            const float* __restrict__ bih0, const float* __restrict__ bhh0,
                            const float* __restrict__ Wih1, const float* __restrict__ Whh1,
                            const float* __restrict__ bih1, const float* __restrict__ bhh1,
                            float* __restrict__ ws) {
    const int blk = blockIdx.x, t = threadIdx.x;
    if (blk < 512) {
        const int r = blk >> 3, wv = blk & 7;
        const int lay = wv >> 2;
        const int mt = wv & 1, kh = (wv & 3) >> 1;
        const int NT = lay ? 16 : 9;
        const int base = SLOT_BASE(r, wv) * 64;
        for (int fl = t; fl < 2 * NT * 64; fl += 256) {
            const int slot = fl >> 6, lane = fl & 63;
            const int kt = slot >> 1, sp = slot & 1;
            const int m = lane & 15, kg = lane >> 4;
            const int q = mt * 2 + (m >> 3), j = m & 7;
            const int row = q * 512 + r * 8 + j;
            u32t out4[4];
            for (int p = 0; p < 4; ++p) {
                u16t h2[2];
                for (int z = 0; z < 2; ++z) {
                    const int e = p * 2 + z;
                    float w;
                    if (lay == 0) {
                        const int k = kh * 288 + kt * 32 + kg * 8 + e;  // inAll-k: [x64 | hA512]
                        w = (k < 64) ? Wih0[row * 64 + k] : Whh0[row * 512 + (k - 64)];
                    } else {
                        const int k = kh * 512 + kt * 32 + kg * 8 + e;  // [hA512 | hB512]
                        w = (k < 512) ? Wih1[row * 512 + k] : Whh1[row * 512 + (k - 512)];
                    }
                    u16t hb, lb;
                    f16split(w, hb, lb);
                    h2[z] = (sp == 0) ? hb : lb;
                }
                out4[p] = (u32t)h2[0] | ((u32t)h2[1] << 16);
            }
            u32t* wd = (u32t*)ws + ((size_t)(base + fl)) * 4;
            wd[0] = out4[0]; wd[1] = out4[1]; wd[2] = out4[2]; wd[3] = out4[3];
        }
    } else {
        for (int u = 0; u < 8; ++u) {
            const int i = t * 8 + u;             // 0..2047
            if (blk == 512) ws[OFF_BS0 + i] = bih0[i] + bhh0[i];
            else            ws[OFF_BS1 + i] = bih1[i] + bhh1[i];
        }
    }
}

// ---------------- persistent MFMA LSTM ----------------
__launch_bounds__(NTHR, 2)
__global__ void lstm_persistent(const float* __restrict__ x,
                                const float* __restrict__ Wlin,
                                const float* __restrict__ blin,
                                float* __restrict__ ws,
                                float* __restrict__ out) {
    const int g = blockIdx.x & 3;          // group
    const int r = blockIdx.x >> 2;         // rank: owns dims r*8..r*8+7
    const int tid = threadIdx.x;
    const int wv = tid >> 6;               // wave 0..7
    const int lane = tid & 63;

    float* __restrict__ ghA = ws + OFF_HA;
    float* __restrict__ ghB = ws + OFF_HB;
    u32t* flags = (u32t*)(ws + OFF_BAR);
    u32t* myflag = flags + (size_t)(g * 64 + r) * 16;
    const u32t* pollp = flags + (size_t)(g * 64 + lane) * 16;

    __shared__ __align__(16) u16t Vhi[16 * KP];           // 35 KB (f16 bits)
    __shared__ __align__(16) u16t Vlo[16 * KP];           // 35 KB (f16 bits, x4096)
    __shared__ __align__(16) float part[8 * 16 * PST];    // 10 KB [slot=wv][m16][b16 str20]
    __shared__ float logit_s[160];

    // ---- stationary weight fragments (whole sequence) ----
    half8 afh[16], afl[16];   // [ktile] hi-plane / scaled-lo-plane
    {
        const half8* wp = (const half8*)ws;
        const size_t fb = (size_t)SLOT_BASE(r, wv) * 64 + lane;
        if (wv < 4) {
#pragma unroll
            for (int t0 = 0; t0 < 9; ++t0) {
                afh[t0] = wp[fb + (t0 * 2 + 0) * 64];
                afl[t0] = wp[fb + (t0 * 2 + 1) * 64];
            }
        } else {
#pragma unroll
            for (int t0 = 0; t0 < 16; ++t0) {
                afh[t0] = wp[fb + (t0 * 2 + 0) * 64];
                afl[t0] = wp[fb + (t0 * 2 + 1) * 64];
            }
        }
    }

    // ---- role constants ----
    const int bcol = lane & 15, kg = lane >> 4;
    const int vrow = bcol * KP + kg * 8;               // B-frag base
    const int sb = tid >> 5, sd = (tid & 31) * 2;      // x staging roles
    const int ul = (tid >> 7) & 1, ub = (tid >> 3) & 15, uj = tid & 7;  // update roles (tid<256)
    const float* bsl = ws + ((tid >> 7) ? OFF_BS1 : OFF_BS0);
    float biasv[4];
#pragma unroll
    for (int q = 0; q < 4; ++q) biasv[q] = bsl[q * 512 + r * 8 + uj];
    float* __restrict__ ghW = ul ? ghB : ghA;
    float creg = 0.f;

    for (int s = 0; s <= Tc; ++s) {
        const int pin = (s + 1) & 1, pout = s & 1;

        // ---------- stage hA, hB (f32 planes, proven protocol) -> f16 hi/lo LDS ----------
        {
            f32x4v stA[4], stB[4];
            const size_t hbase = ((size_t)pin * 4 + g) * (16 * 512);
            const float* pA = ghA + hbase + 4 * tid;
            const float* pB = ghB + hbase + 4 * tid;
#pragma unroll
            for (int u = 0; u < 4; ++u)
                asm volatile("global_load_dwordx4 %0, %1, off sc0 sc1"
                             : "=v"(stA[u]) : "v"(pA + 2048 * u));
#pragma unroll
            for (int u = 0; u < 4; ++u)
                asm volatile("global_load_dwordx4 %0, %1, off sc0 sc1"
                             : "=v"(stB[u]) : "v"(pB + 2048 * u));
            f32x2 xv;
            if (s < Tc)
                xv = *(const f32x2*)&x[(((size_t)(g * 16 + sb)) * Tc + s) * 64 + sd];
            asm volatile("s_waitcnt vmcnt(0)" ::: "memory");
#pragma unroll
            for (int u = 0; u < 4; ++u) {
                const int c = tid + 512 * u;         // f32 quad id
                const int b = c >> 7, d0 = (c & 127) * 4;
                stash4(&Vhi[b * KP + 64  + d0], &Vlo[b * KP + 64  + d0], stA[u]);
                stash4(&Vhi[b * KP + 576 + d0], &Vlo[b * KP + 576 + d0], stB[u]);
            }
            if (s < Tc) {
                u16t h0, l0, h1, l1;
                f16split(xv.x, h0, l0);
                f16split(xv.y, h1, l1);
                *(u32t*)&Vhi[sb * KP + sd] = (u32t)h0 | ((u32t)h1 << 16);
                *(u32t*)&Vlo[sb * KP + sd] = (u32t)l0 | ((u32t)l1 << 16);
            }
        }
        __syncthreads();   // #1

        // ---------- MFMA: G = (Wh+Wl/4096)·(Vh+Vl/4096), drop lo·lo ----------
        {
            const bool mact = (wv < 4) ? (s < Tc) : (s >= 1);
            if (mact) {
                f32x4v aH = {0.f, 0.f, 0.f, 0.f};
                f32x4v aM = {0.f, 0.f, 0.f, 0.f};
                if (wv < 4) {
                    const int kb = ((wv & 3) >> 1) * 288;   // layer0: K=[x|hA], khalf of 288
#pragma unroll
                    for (int t0 = 0; t0 < 9; ++t0) {
                        const half8 bh = *(const half8*)&Vhi[vrow + kb + t0 * 32];
                        const half8 bl = *(const half8*)&Vlo[vrow + kb + t0 * 32];
                        aH = __builtin_amdgcn_mfma_f32_16x16x32_f16(afh[t0], bh, aH, 0, 0, 0);
                        aM = __builtin_amdgcn_mfma_f32_16x16x32_f16(afh[t0], bl, aM, 0, 0, 0);
                        aM = __builtin_amdgcn_mfma_f32_16x16x32_f16(afl[t0], bh, aM, 0, 0, 0);
                    }
                } else {
                    const int kb = 64 + (((wv - 4) >> 1) & 1) * 512;  // layer1: K=[hA|hB]
#pragma unroll
                    for (int t0 = 0; t0 < 16; ++t0) {
                        const half8 bh = *(const half8*)&Vhi[vrow + kb + t0 * 32];
                        const half8 bl = *(const half8*)&Vlo[vrow + kb + t0 * 32];
                        aH = __builtin_amdgcn_mfma_f32_16x16x32_f16(afh[t0], bh, aH, 0, 0, 0);
                        aM = __builtin_amdgcn_mfma_f32_16x16x32_f16(afh[t0], bl, aM, 0, 0, 0);
                        aM = __builtin_amdgcn_mfma_f32_16x16x32_f16(afl[t0], bh, aM, 0, 0, 0);
                    }
                }
                const f32x4v ac = aH + aM * 2.44140625e-4f;   // + accM / 4096
                // C layout (m89-verified): col=lane&15 (batch), row=(lane>>4)*4+i (gate-row m)
                float* pw = &part[wv * 320 + (kg * 4) * PST + bcol];
#pragma unroll
                for (int i = 0; i < 4; ++i) pw[i * PST] = ac[i];
            }
        }
        __syncthreads();   // #2

        // ---------- gate sums (clamped, transparent) + cell update ----------
        if (tid < 256) {
            const bool act = ul ? (s >= 1) : (s < Tc);
            if (act) {
                float gg[4];
#pragma unroll
                for (int q = 0; q < 4; ++q) {
                    const int mt = q >> 1, m = (q & 1) * 8 + uj;
                    const float raw = biasv[q]
                        + part[(ul * 4 + mt) * 320 + m * PST + ub]        // khalf 0
                        + part[(ul * 4 + 2 + mt) * 320 + m * PST + ub];   // khalf 1
                    gg[q] = fminf(fmaxf(raw, -60.f), 60.f);
                }
                const float iv = sigmf(gg[0]);
                const float fv = sigmf(gg[1]);
                const float gv_ = tanhf(gg[2]);
                const float ov = sigmf(gg[3]);
                creg = fv * creg + iv * gv_;
                const float hv = ov * tanhf(creg);
                ASTORE(&ghW[(((size_t)pout * 4 + g) * 16 + ub) * 512 + r * 8 + uj], hv);
            }
        }
        __syncthreads();   // #3: implicit drain of tracked atomic h stores (proven)

        // ---------- flag publish + distributed poll (wave 0) — proven ----------
        if (tid == 0) ASTORE(myflag, (u32t)(s + 1));
        if (wv == 0) {
            const u32t tgt = (u32t)(s + 1);
            u32t v;
            for (;;) {
                asm volatile("global_load_dword %0, %1, off sc0 sc1\n\ts_waitcnt vmcnt(0)"
                             : "=v"(v) : "v"(pollp) : "memory");
                if (__all((int)(v >= tgt))) break;
                __builtin_amdgcn_s_sleep(1);
            }
        }
        __syncthreads();   // #4
    }

    // ---------- final projection + log_softmax (one block per group, f32 path) ----------
    if (r == 0) {
        float* Vf = (float*)Vhi;   // 8768 f32 scratch >= 8192 needed
        {
            const float* hf = ghB + (((size_t)(Tc & 1) * 4 + g) * 16 + sb) * 512 + (tid & 31) * 16;
            float* d = &Vf[sb * 512 + (tid & 31) * 16];
            for (int k = 0; k < 16; ++k) d[k] = ALOAD(hf + k);
        }
        __syncthreads();
        if (tid < 16 * OUTc) {
            const int o = tid % OUTc, b = tid / OUTc;
            float sum = blin[o];
            for (int k = 0; k < 512; ++k) sum = fmaf(Wlin[o * 512 + k], Vf[b * 512 + k], sum);
            logit_s[b * OUTc + o] = sum;
        }
        __syncthreads();
        if (tid < 16) {
            float m = -1e30f;
#pragma unroll
            for (int o = 0; o < OUTc; ++o) m = fmaxf(m, logit_s[tid * OUTc + o]);
            float se = 0.f;
#pragma unroll
            for (int o = 0; o < OUTc; ++o) se += expf(logit_s[tid * OUTc + o] - m);
            const float lse = m + logf(se);
#pragma unroll
            for (int o = 0; o < OUTc; ++o)
                out[((size_t)(g * 16 + tid)) * OUTc + o] = logit_s[tid * OUTc + o] - lse;
        }
    }
}

extern "C" void kernel_launch(void* const* d_in, const int* in_sizes, int n_in,
                              void* d_out, int out_size, void* d_ws, size_t ws_size,
                              hipStream_t stream) {
    (void)in_sizes; (void)n_in; (void)out_size; (void)ws_size;
    const float* x    = (const float*)d_in[0];
    const float* Wih0 = (const float*)d_in[1];
    const float* Whh0 = (const float*)d_in[2];
    const float* bih0 = (const float*)d_in[3];
    const float* bhh0 = (const float*)d_in[4];
    const float* Wih1 = (const float*)d_in[5];
    const float* Whh1 = (const float*)d_in[6];
    const float* bih1 = (const float*)d_in[7];
    const float* bhh1 = (const float*)d_in[8];
    const float* Wlin = (const float*)d_in[9];
    const float* blin = (const float*)d_in[10];
    float* ws  = (float*)d_ws;
    float* out = (float*)d_out;

    // zero f32 h double-buffers + flags (ws is re-poisoned 0xAA before every timed launch)
    hipMemsetAsync((char*)d_ws + (size_t)OFF_HA * 4, 0,
                   (size_t)(WS_FLOATS - OFF_HA) * 4, stream);

    // build compact fp16 hi/lo MFMA fragments + bias sums
    prep_kernel<<<514, 256, 0, stream>>>(Wih0, Whh0, bih0, bhh0,
                                         Wih1, Whh1, bih1, bhh1, ws);

    // persistent weight-stationary MFMA LSTM: 256 blocks (1/CU, 8 waves), 4 groups
    lstm_persistent<<<NGRP * BPG, NTHR, 0, stream>>>(x, Wlin, blin, ws, out);
}